// Round 6
// baseline (332.649 us; speedup 1.0000x reference)
//
#include <hip/hip_runtime.h>
#include <stdint.h>

#define BATCH 2
#define NANCH 100000
#define NCLS 80
#define TOPK 300
#define NSLICE (BATCH * NCLS)                 // 160
#define CAND 2048
#define FLATN (NCLS * TOPK)                   // 24000
#define ELEMS_PER_IMG (NANCH * NCLS)          // 8,000,000
#define F4TOTAL ((BATCH * ELEMS_PER_IMG) / 4) // 4,000,000
#define CUT 0.992f                            // expected ~800 cand/slice on uniform data
#define CHUNK_F4 2048                         // 256 thr x 8 f4
#define NBLK ((F4TOTAL + CHUNK_F4 - 1) / CHUNK_F4)  // 1954
#define NBPAD 2048

// ---------- IoU, bit-exact vs reference (no FMA contraction) ----------
__device__ __forceinline__ bool iou_gt_half(float4 a, float4 b) {
#pragma clang fp contract(off)
    float areaA = (a.z - a.x) * (a.w - a.y);
    float areaB = (b.z - b.x) * (b.w - b.y);
    float ty = fmaxf(a.x, b.x);
    float tx = fmaxf(a.y, b.y);
    float by = fminf(a.z, b.z);
    float bx = fminf(a.w, b.w);
    float hh = fmaxf(by - ty, 0.0f);
    float ww = fmaxf(bx - tx, 0.0f);
    float inter = hh * ww;
    float un = (areaA + areaB) - inter;
    float iou = inter / fmaxf(un, 1e-8f);
    return iou > 0.5f;
}

// ---------- K1: per-block per-slice counts (no global atomics) ----------
__global__ __launch_bounds__(256) void k1_count(const float* __restrict__ cls,
                                                uint32_t* __restrict__ blockcnt) {
    __shared__ uint32_t cnt[NSLICE];
    const int tid = threadIdx.x, blk = blockIdx.x;
    for (int i = tid; i < NSLICE; i += 256) cnt[i] = 0;
    __syncthreads();
    const float4* p = reinterpret_cast<const float4*>(cls);
    const int base = blk * CHUNK_F4;
#pragma unroll
    for (int j = 0; j < 8; ++j) {
        int i = base + j * 256 + tid;
        if (i < F4TOTAL) {
            float4 v = p[i];
            if (v.x >= CUT || v.y >= CUT || v.z >= CUT || v.w >= CUT) {
                uint32_t eg = (uint32_t)i * 4u;
                int b = (eg >= (uint32_t)ELEMS_PER_IMG) ? 1 : 0;
                uint32_t e = eg - (uint32_t)b * (uint32_t)ELEMS_PER_IMG;
                uint32_t c = e % NCLS;
                float arr[4] = {v.x, v.y, v.z, v.w};
#pragma unroll
                for (int q = 0; q < 4; ++q)
                    if (arr[q] >= CUT) atomicAdd(&cnt[b * NCLS + (int)c + q], 1u);
            }
        }
    }
    __syncthreads();
    for (int s = tid; s < NSLICE; s += 256) blockcnt[(size_t)s * NBPAD + blk] = cnt[s];
}

// ---------- K2: per-slice exclusive prefix scan over blocks ----------
__global__ __launch_bounds__(256) void k2_scan(const uint32_t* __restrict__ blockcnt,
                                               uint32_t* __restrict__ blockbase,
                                               uint32_t* __restrict__ ccount) {
    __shared__ uint32_t A[NBPAD], B[NBPAD];
    const int s = blockIdx.x, tid = threadIdx.x;
    for (int i = tid; i < NBPAD; i += 256)
        A[i] = (i >= 1 && i <= NBLK) ? blockcnt[(size_t)s * NBPAD + i - 1] : 0u;
    __syncthreads();
    uint32_t* src = A;
    uint32_t* dst = B;
    for (int off = 1; off < NBPAD; off <<= 1) {
        for (int i = tid; i < NBPAD; i += 256)
            dst[i] = src[i] + ((i >= off) ? src[i - off] : 0u);
        __syncthreads();
        uint32_t* t = src; src = dst; dst = t;
    }
    for (int i = tid; i < NBLK; i += 256) blockbase[(size_t)s * NBPAD + i] = src[i];
    if (tid == 0) ccount[s] = src[NBLK];
}

// ---------- K3: emit candidates to exclusive reserved positions ----------
__global__ __launch_bounds__(256) void k3_emit(const float* __restrict__ cls,
                                               const uint32_t* __restrict__ blockbase,
                                               uint64_t* __restrict__ cand) {
    __shared__ uint32_t cur[NSLICE];
    const int tid = threadIdx.x, blk = blockIdx.x;
    for (int i = tid; i < NSLICE; i += 256) cur[i] = 0;
    __syncthreads();
    const float4* p = reinterpret_cast<const float4*>(cls);
    const int base = blk * CHUNK_F4;
#pragma unroll
    for (int j = 0; j < 8; ++j) {
        int i = base + j * 256 + tid;
        if (i < F4TOTAL) {
            float4 v = p[i];
            if (v.x >= CUT || v.y >= CUT || v.z >= CUT || v.w >= CUT) {
                uint32_t eg = (uint32_t)i * 4u;
                int b = (eg >= (uint32_t)ELEMS_PER_IMG) ? 1 : 0;
                uint32_t e = eg - (uint32_t)b * (uint32_t)ELEMS_PER_IMG;
                uint32_t n = e / NCLS;
                uint32_t c = e - n * NCLS;
                float arr[4] = {v.x, v.y, v.z, v.w};
#pragma unroll
                for (int q = 0; q < 4; ++q) {
                    float s = arr[q];
                    if (s >= CUT) {
                        int slice = b * NCLS + (int)c + q;
                        uint32_t off = atomicAdd(&cur[slice], 1u);
                        uint32_t pos = blockbase[(size_t)slice * NBPAD + blk] + off;
                        if (pos < CAND)
                            cand[(size_t)slice * CAND + pos] =
                                ((uint64_t)__float_as_uint(s) << 32) | (uint64_t)(~n);
                    }
                }
            }
        }
    }
}

// ---------- K4: generic fixup (exits immediately when superset is valid) ----------
__global__ __launch_bounds__(256) void k4_fixup(const float* __restrict__ cls,
                                                uint32_t* __restrict__ ccount,
                                                uint64_t* __restrict__ cand) {
    const int slice = blockIdx.x;
    const uint32_t cnt0 = ccount[slice];
    if (cnt0 >= (uint32_t)TOPK && cnt0 <= (uint32_t)CAND) return;  // fast path
    const int b = slice / NCLS, c = slice % NCLS;
    const float* col = cls + (size_t)b * ELEMS_PER_IMG + c;
    __shared__ uint32_t h[128];
    __shared__ uint32_t nvalid;
    __shared__ int Tb;
    const int tid = threadIdx.x;
    for (int i = tid; i < 128; i += 256) h[i] = 0;
    if (tid == 0) nvalid = 0;
    __syncthreads();
    for (int i = tid; i < NANCH; i += 256) {
        float s = col[(size_t)i * NCLS];
        if (s > 0.05f) {
            int bn = min((int)(fminf(s, 0.9999999f) * 128.0f), 127);
            atomicAdd(&h[bn], 1u);
            atomicAdd(&nvalid, 1u);
        }
    }
    __syncthreads();
    if (tid == 0) {
        uint32_t need = min((uint32_t)TOPK, nvalid);
        uint32_t cum = 0;
        int T = 0;
        if (need > 0) {
            for (int d = 127; d >= 0; --d) {
                if (cum + h[d] >= need) { T = d; break; }
                cum += h[d];
            }
        } else {
            T = 128;
        }
        Tb = T;
        ccount[slice] = 0;
    }
    __syncthreads();
    const int T = Tb;
    for (int i = tid; i < NANCH; i += 256) {
        float s = col[(size_t)i * NCLS];
        if (s > 0.05f) {
            int bn = min((int)(fminf(s, 0.9999999f) * 128.0f), 127);
            if (bn >= T) {
                uint32_t slot = atomicAdd(&ccount[slice], 1u);
                if (slot < CAND)
                    cand[(size_t)slice * CAND + slot] =
                        ((uint64_t)__float_as_uint(s) << 32) | (uint64_t)(~(uint32_t)i);
            }
        }
    }
}

// ---------- K5: per-slice sort + NMS + stage ----------
__global__ __launch_bounds__(512) void k5_nms(const float* __restrict__ boxes,
                                              const uint32_t* __restrict__ ccount,
                                              const uint64_t* __restrict__ cand,
                                              uint64_t* __restrict__ staged,
                                              int* __restrict__ nsel) {
    __shared__ uint64_t keys[CAND];
    __shared__ float4 box[TOPK];
    __shared__ uint32_t rowm[TOPK * 10];
    __shared__ uint8_t kept[TOPK];
    const int tid = threadIdx.x;
    const int slice = blockIdx.x;
    const int b = slice / NCLS, c = slice % NCLS;
    const uint32_t cnt = min(ccount[slice], (uint32_t)CAND);
    const int SN = (cnt <= 1024u) ? 1024 : 2048;
    for (int i = tid; i < SN; i += 512)
        keys[i] = (i < (int)cnt) ? cand[(size_t)slice * CAND + i] : 0ull;

    for (int k = 2; k <= SN; k <<= 1) {
        for (int j = k >> 1; j > 0; j >>= 1) {
            __syncthreads();
            for (int i = tid; i < SN; i += 512) {
                int p = i ^ j;
                if (p > i) {
                    uint64_t a = keys[i], bb = keys[p];
                    if ((a > bb) == ((i & k) == 0)) { keys[i] = bb; keys[p] = a; }
                }
            }
        }
    }
    __syncthreads();

    for (int r = tid; r < TOPK; r += 512) {
        uint64_t sk = keys[SN - 1 - r];
        uint32_t n = sk ? ~(uint32_t)sk : 0u;
        box[r] = reinterpret_cast<const float4*>(boxes)[(size_t)b * NANCH + n];
    }
    for (int i = tid; i < TOPK * 10; i += 512) rowm[i] = 0;
    __syncthreads();

    for (int t = tid; t < TOPK * TOPK; t += 512) {
        int r1 = t / TOPK, r2 = t - r1 * TOPK;
        if (r2 < r1) {
            if (iou_gt_half(box[r1], box[r2]))
                atomicOr(&rowm[r1 * 10 + (r2 >> 5)], 1u << (r2 & 31));
        }
    }
    __syncthreads();

    if (tid < 64) {
        uint32_t M = 0;
        for (int i = 0; i < TOPK; ++i) {
            bool valid = keys[SN - 1 - i] != 0ull;
            uint32_t ov = (tid < 10) ? (rowm[i * 10 + tid] & M) : 0u;
            bool sup = __any(ov != 0u);
            bool keep = valid && !sup;
            if (keep && tid == (i >> 5)) M |= (1u << (i & 31));
            if (tid == 0) kept[i] = keep ? 1 : 0;
        }
    }
    __syncthreads();

    for (int r = tid; r < TOPK; r += 512) {
        uint64_t sk = keys[SN - 1 - r];
        uint32_t flat = (uint32_t)c * TOPK + (uint32_t)r;
        uint32_t n = sk ? ~(uint32_t)sk : 0u;
        nsel[(size_t)b * FLATN + flat] = (int)n;
        staged[(size_t)b * FLATN + flat] =
            (kept[r] ? ((sk & 0xFFFFFFFF00000000ull) | (uint64_t)(~flat)) : 0ull);
    }
}

// ---------- K6: per-image top-300 of 24000, keys in registers, wave-parallel ----------
__global__ __launch_bounds__(1024) void k6_final(const float* __restrict__ boxes,
                                                 const uint64_t* __restrict__ staged,
                                                 const int* __restrict__ nsel,
                                                 float* __restrict__ out) {
    __shared__ uint32_t hist[256];
    __shared__ uint64_t sel[512];
    __shared__ uint64_t rankedKey[TOPK];
    __shared__ uint64_t threshS;
    __shared__ uint32_t selCount, pickS, needS, doneS;
    const int tid = threadIdx.x;
    const int lane = tid & 63;
    const int b = blockIdx.x;
    const uint64_t* keys = staged + (size_t)b * FLATN;

    // load 24000 keys once into registers (coalesced, statically indexed)
    uint64_t kk[24];
    uint32_t aliveMask = 0;
#pragma unroll
    for (int j = 0; j < 24; ++j) {
        int i = tid + j * 1024;
        uint64_t v = (i < FLATN) ? keys[i] : 0ull;
        kk[j] = v;
        if (v != 0ull) aliveMask |= (1u << j);
    }
    if (tid == 0) { threshS = 0ull; selCount = 0; needS = TOPK; doneS = 0; }
    for (int i = tid; i < 512; i += 1024) sel[i] = 0ull;
    for (int i = tid; i < TOPK; i += 1024) rankedKey[i] = 0ull;
    __syncthreads();

    for (int r = 7; r >= 0; --r) {
        if (doneS) break;  // uniform (barrier-separated)
        if (tid < 256) hist[tid] = 0;
        __syncthreads();
        const int shift = r * 8;
        // wave-aggregated histogram (scores cluster -> same-bucket waves -> 1 atomic/wave)
#pragma unroll
        for (int j = 0; j < 24; ++j) {
            bool a = (aliveMask >> j) & 1u;
            uint32_t bkt = (uint32_t)(kk[j] >> shift) & 255u;
            unsigned long long m = __ballot(a);
            while (m) {
                int lead = (int)(__ffsll(m) - 1);
                uint32_t bl = __shfl(bkt, lead);
                bool same = a && (bkt == bl);
                unsigned long long sm = __ballot(same);
                if (lane == lead) atomicAdd(&hist[bl], (uint32_t)__popcll(sm));
                m &= ~sm;
                a = a && !same;
            }
        }
        __syncthreads();
        // wave-parallel suffix scan + pick (wave 0 only, no barriers inside)
        if (tid < 64) {
            const int l = tid;
            uint32_t h0 = hist[4 * l + 0], h1 = hist[4 * l + 1];
            uint32_t h2 = hist[4 * l + 2], h3 = hist[4 * l + 3];
            uint32_t s3 = h3, s2 = h2 + s3, s1 = h1 + s2, s0 = h0 + s1;
            uint32_t x = s0;
            for (int off = 1; off < 64; off <<= 1) {
                uint32_t y = __shfl_down(x, off);
                if (l + off < 64) x += y;
            }
            uint32_t above = x - s0;  // suffix over lanes > l
            uint32_t sf[4] = {s0 + above, s1 + above, s2 + above, s3 + above};
            uint32_t nxv[4] = {s1 + above, s2 + above, s3 + above, above};  // suffix[d+1]
            uint32_t hh[4] = {h0, h1, h2, h3};
            uint32_t need = needS;
            uint32_t tot = __shfl(x, 0);
            if (r == 7 && tot < need) {
                if (l == 0) { doneS = 1; threshS = 1ull; }  // select all nonzero
            } else {
#pragma unroll
                for (int q = 0; q < 4; ++q) {
                    if (sf[q] >= need && nxv[q] < need) {
                        uint32_t nn = need - nxv[q];
                        uint32_t pk = (uint32_t)(4 * l + q);
                        pickS = pk;
                        needS = nn;
                        threshS |= ((uint64_t)pk) << shift;
                        if (hh[q] == nn) doneS = 1;  // whole bucket taken; low bytes 0
                    }
                }
            }
        }
        __syncthreads();
        if (!doneS) {
            const uint32_t pick = pickS;
#pragma unroll
            for (int j = 0; j < 24; ++j)
                if (((uint32_t)(kk[j] >> shift) & 255u) != pick) aliveMask &= ~(1u << j);
        }
        __syncthreads();
    }
    const uint64_t thresh = threshS;

    // collect selected (<= 300 by construction)
#pragma unroll
    for (int j = 0; j < 24; ++j) {
        uint64_t v = kk[j];
        if (v != 0ull && v >= thresh) {
            uint32_t pos = atomicAdd(&selCount, 1u);
            if (pos < 512) sel[pos] = v;
        }
    }
    __syncthreads();

    // rank-by-counting (keys unique; sel[j2] reads broadcast across lanes)
    for (int s = tid; s < 512; s += 1024) {
        uint64_t mine = sel[s];
        if (mine != 0ull) {
            int rank = 0;
            for (int j2 = 0; j2 < 512; ++j2) rank += (sel[j2] > mine) ? 1 : 0;
            if (rank < TOPK) rankedKey[rank] = mine;
        }
    }
    __syncthreads();

    float* outBoxes = out;
    float* outScores = out + BATCH * TOPK * 4;
    float* outLabels = out + BATCH * TOPK * 4 + BATCH * TOPK;
    for (int r0 = tid; r0 < TOPK; r0 += 1024) {
        uint64_t kkv = rankedKey[r0];
        if (kkv != 0ull) {
            uint32_t flat = ~(uint32_t)kkv;
            uint32_t c = flat / TOPK;
            uint32_t n = (uint32_t)nsel[(size_t)b * FLATN + flat];
            float4 bx = reinterpret_cast<const float4*>(boxes)[(size_t)b * NANCH + n];
            reinterpret_cast<float4*>(outBoxes)[(size_t)b * TOPK + r0] = bx;
            outScores[b * TOPK + r0] = __uint_as_float((uint32_t)(kkv >> 32));
            outLabels[b * TOPK + r0] = (float)c;
        } else {
            reinterpret_cast<float4*>(outBoxes)[(size_t)b * TOPK + r0] =
                make_float4(-1.0f, -1.0f, -1.0f, -1.0f);
            outScores[b * TOPK + r0] = -1.0f;
            outLabels[b * TOPK + r0] = -1.0f;
        }
    }
}

extern "C" void kernel_launch(void* const* d_in, const int* in_sizes, int n_in,
                              void* d_out, int out_size, void* d_ws, size_t ws_size,
                              hipStream_t stream) {
    const float* boxes = (const float*)d_in[0];          // [2,100000,4]
    const float* cls   = (const float*)d_in[1];          // [2,100000,80]
    float* out = (float*)d_out;                          // 3600 floats
    char* ws = (char*)d_ws;

    size_t off = 0;
    uint32_t* blockcnt = (uint32_t*)(ws + off);
    off += (size_t)NSLICE * NBPAD * 4;                   // 1,310,720
    uint32_t* blockbase = (uint32_t*)(ws + off);
    off += (size_t)NSLICE * NBPAD * 4;                   // 1,310,720
    uint32_t* ccount = (uint32_t*)(ws + off); off += 4096;
    uint64_t* cand = (uint64_t*)(ws + off);
    off += (size_t)NSLICE * CAND * 8;                    // 2,621,440
    uint64_t* staged = (uint64_t*)(ws + off);
    off += (size_t)BATCH * FLATN * 8;                    // 384,000
    int* nsel = (int*)(ws + off);
    off += (size_t)BATCH * FLATN * 4;                    // 192,000

    k1_count<<<NBLK, 256, 0, stream>>>(cls, blockcnt);
    k2_scan<<<NSLICE, 256, 0, stream>>>(blockcnt, blockbase, ccount);
    k3_emit<<<NBLK, 256, 0, stream>>>(cls, blockbase, cand);
    k4_fixup<<<NSLICE, 256, 0, stream>>>(cls, ccount, cand);
    k5_nms<<<NSLICE, 512, 0, stream>>>(boxes, ccount, cand, staged, nsel);
    k6_final<<<BATCH, 1024, 0, stream>>>(boxes, staged, nsel, out);
}

// Round 7
// 260.345 us; speedup vs baseline: 1.2777x; 1.2777x over previous
//
#include <hip/hip_runtime.h>
#include <stdint.h>

#define BATCH 2
#define NANCH 100000
#define NCLS 80
#define TOPK 300
#define NSLICE (BATCH * NCLS)                 // 160
#define CAND 2048
#define FLATN (NCLS * TOPK)                   // 24000
#define ELEMS_PER_IMG (NANCH * NCLS)          // 8,000,000
#define F4TOTAL ((BATCH * ELEMS_PER_IMG) / 4) // 4,000,000
#define CUT 0.992f                            // expected ~800 cand/slice on uniform data
#define CHUNK_F4 2048                         // 256 thr x 8 f4
#define NBLK ((F4TOTAL + CHUNK_F4 - 1) / CHUNK_F4)  // 1954
#define NBPAD 2048

// ---------- IoU, bit-exact vs reference (no FMA contraction) ----------
__device__ __forceinline__ bool iou_gt_half(float4 a, float4 b) {
#pragma clang fp contract(off)
    float areaA = (a.z - a.x) * (a.w - a.y);
    float areaB = (b.z - b.x) * (b.w - b.y);
    float ty = fmaxf(a.x, b.x);
    float tx = fmaxf(a.y, b.y);
    float by = fminf(a.z, b.z);
    float bx = fminf(a.w, b.w);
    float hh = fmaxf(by - ty, 0.0f);
    float ww = fmaxf(bx - tx, 0.0f);
    float inter = hh * ww;
    float un = (areaA + areaB) - inter;
    float iou = inter / fmaxf(un, 1e-8f);
    return iou > 0.5f;
}

// ---------- K1: per-block per-slice counts (no global atomics) ----------
__global__ __launch_bounds__(256) void k1_count(const float* __restrict__ cls,
                                                uint32_t* __restrict__ blockcnt) {
    __shared__ uint32_t cnt[NSLICE];
    const int tid = threadIdx.x, blk = blockIdx.x;
    for (int i = tid; i < NSLICE; i += 256) cnt[i] = 0;
    __syncthreads();
    const float4* p = reinterpret_cast<const float4*>(cls);
    const int base = blk * CHUNK_F4;
#pragma unroll
    for (int j = 0; j < 8; ++j) {
        int i = base + j * 256 + tid;
        if (i < F4TOTAL) {
            float4 v = p[i];
            if (v.x >= CUT || v.y >= CUT || v.z >= CUT || v.w >= CUT) {
                uint32_t eg = (uint32_t)i * 4u;
                int b = (eg >= (uint32_t)ELEMS_PER_IMG) ? 1 : 0;
                uint32_t e = eg - (uint32_t)b * (uint32_t)ELEMS_PER_IMG;
                uint32_t c = e % NCLS;
                float arr[4] = {v.x, v.y, v.z, v.w};
#pragma unroll
                for (int q = 0; q < 4; ++q)
                    if (arr[q] >= CUT) atomicAdd(&cnt[b * NCLS + (int)c + q], 1u);
            }
        }
    }
    __syncthreads();
    for (int s = tid; s < NSLICE; s += 256) blockcnt[(size_t)s * NBPAD + blk] = cnt[s];
}

// ---------- K2: per-slice exclusive prefix scan over blocks ----------
__global__ __launch_bounds__(256) void k2_scan(const uint32_t* __restrict__ blockcnt,
                                               uint32_t* __restrict__ blockbase,
                                               uint32_t* __restrict__ ccount) {
    __shared__ uint32_t A[NBPAD], B[NBPAD];
    const int s = blockIdx.x, tid = threadIdx.x;
    for (int i = tid; i < NBPAD; i += 256)
        A[i] = (i >= 1 && i <= NBLK) ? blockcnt[(size_t)s * NBPAD + i - 1] : 0u;
    __syncthreads();
    uint32_t* src = A;
    uint32_t* dst = B;
    for (int off = 1; off < NBPAD; off <<= 1) {
        for (int i = tid; i < NBPAD; i += 256)
            dst[i] = src[i] + ((i >= off) ? src[i - off] : 0u);
        __syncthreads();
        uint32_t* t = src; src = dst; dst = t;
    }
    for (int i = tid; i < NBLK; i += 256) blockbase[(size_t)s * NBPAD + i] = src[i];
    if (tid == 0) ccount[s] = src[NBLK];
}

// ---------- K3: emit candidates to exclusive reserved positions ----------
__global__ __launch_bounds__(256) void k3_emit(const float* __restrict__ cls,
                                               const uint32_t* __restrict__ blockbase,
                                               uint64_t* __restrict__ cand) {
    __shared__ uint32_t cur[NSLICE];
    const int tid = threadIdx.x, blk = blockIdx.x;
    for (int i = tid; i < NSLICE; i += 256) cur[i] = 0;
    __syncthreads();
    const float4* p = reinterpret_cast<const float4*>(cls);
    const int base = blk * CHUNK_F4;
#pragma unroll
    for (int j = 0; j < 8; ++j) {
        int i = base + j * 256 + tid;
        if (i < F4TOTAL) {
            float4 v = p[i];
            if (v.x >= CUT || v.y >= CUT || v.z >= CUT || v.w >= CUT) {
                uint32_t eg = (uint32_t)i * 4u;
                int b = (eg >= (uint32_t)ELEMS_PER_IMG) ? 1 : 0;
                uint32_t e = eg - (uint32_t)b * (uint32_t)ELEMS_PER_IMG;
                uint32_t n = e / NCLS;
                uint32_t c = e - n * NCLS;
                float arr[4] = {v.x, v.y, v.z, v.w};
#pragma unroll
                for (int q = 0; q < 4; ++q) {
                    float s = arr[q];
                    if (s >= CUT) {
                        int slice = b * NCLS + (int)c + q;
                        uint32_t off = atomicAdd(&cur[slice], 1u);
                        uint32_t pos = blockbase[(size_t)slice * NBPAD + blk] + off;
                        if (pos < CAND)
                            cand[(size_t)slice * CAND + pos] =
                                ((uint64_t)__float_as_uint(s) << 32) | (uint64_t)(~n);
                    }
                }
            }
        }
    }
}

// ---------- K4: generic fixup (exits immediately when superset is valid) ----------
__global__ __launch_bounds__(256) void k4_fixup(const float* __restrict__ cls,
                                                uint32_t* __restrict__ ccount,
                                                uint64_t* __restrict__ cand) {
    const int slice = blockIdx.x;
    const uint32_t cnt0 = ccount[slice];
    if (cnt0 >= (uint32_t)TOPK && cnt0 <= (uint32_t)CAND) return;  // fast path
    const int b = slice / NCLS, c = slice % NCLS;
    const float* col = cls + (size_t)b * ELEMS_PER_IMG + c;
    __shared__ uint32_t h[128];
    __shared__ uint32_t nvalid;
    __shared__ int Tb;
    const int tid = threadIdx.x;
    for (int i = tid; i < 128; i += 256) h[i] = 0;
    if (tid == 0) nvalid = 0;
    __syncthreads();
    for (int i = tid; i < NANCH; i += 256) {
        float s = col[(size_t)i * NCLS];
        if (s > 0.05f) {
            int bn = min((int)(fminf(s, 0.9999999f) * 128.0f), 127);
            atomicAdd(&h[bn], 1u);
            atomicAdd(&nvalid, 1u);
        }
    }
    __syncthreads();
    if (tid == 0) {
        uint32_t need = min((uint32_t)TOPK, nvalid);
        uint32_t cum = 0;
        int T = 0;
        if (need > 0) {
            for (int d = 127; d >= 0; --d) {
                if (cum + h[d] >= need) { T = d; break; }
                cum += h[d];
            }
        } else {
            T = 128;
        }
        Tb = T;
        ccount[slice] = 0;
    }
    __syncthreads();
    const int T = Tb;
    for (int i = tid; i < NANCH; i += 256) {
        float s = col[(size_t)i * NCLS];
        if (s > 0.05f) {
            int bn = min((int)(fminf(s, 0.9999999f) * 128.0f), 127);
            if (bn >= T) {
                uint32_t slot = atomicAdd(&ccount[slice], 1u);
                if (slot < CAND)
                    cand[(size_t)slice * CAND + slot] =
                        ((uint64_t)__float_as_uint(s) << 32) | (uint64_t)(~(uint32_t)i);
            }
        }
    }
}

// ---------- K5: per-slice sort + NMS + stage ----------
__global__ __launch_bounds__(512) void k5_nms(const float* __restrict__ boxes,
                                              const uint32_t* __restrict__ ccount,
                                              const uint64_t* __restrict__ cand,
                                              uint64_t* __restrict__ staged,
                                              int* __restrict__ nsel) {
    __shared__ uint64_t keys[CAND];
    __shared__ float4 box[TOPK];
    __shared__ uint32_t rowm[TOPK * 10];
    __shared__ uint8_t kept[TOPK];
    const int tid = threadIdx.x;
    const int slice = blockIdx.x;
    const int b = slice / NCLS, c = slice % NCLS;
    const uint32_t cnt = min(ccount[slice], (uint32_t)CAND);
    const int SN = (cnt <= 1024u) ? 1024 : 2048;
    for (int i = tid; i < SN; i += 512)
        keys[i] = (i < (int)cnt) ? cand[(size_t)slice * CAND + i] : 0ull;

    for (int k = 2; k <= SN; k <<= 1) {
        for (int j = k >> 1; j > 0; j >>= 1) {
            __syncthreads();
            for (int i = tid; i < SN; i += 512) {
                int p = i ^ j;
                if (p > i) {
                    uint64_t a = keys[i], bb = keys[p];
                    if ((a > bb) == ((i & k) == 0)) { keys[i] = bb; keys[p] = a; }
                }
            }
        }
    }
    __syncthreads();

    for (int r = tid; r < TOPK; r += 512) {
        uint64_t sk = keys[SN - 1 - r];
        uint32_t n = sk ? ~(uint32_t)sk : 0u;
        box[r] = reinterpret_cast<const float4*>(boxes)[(size_t)b * NANCH + n];
    }
    for (int i = tid; i < TOPK * 10; i += 512) rowm[i] = 0;
    __syncthreads();

    for (int t = tid; t < TOPK * TOPK; t += 512) {
        int r1 = t / TOPK, r2 = t - r1 * TOPK;
        if (r2 < r1) {
            if (iou_gt_half(box[r1], box[r2]))
                atomicOr(&rowm[r1 * 10 + (r2 >> 5)], 1u << (r2 & 31));
        }
    }
    __syncthreads();

    if (tid < 64) {
        uint32_t M = 0;
        for (int i = 0; i < TOPK; ++i) {
            bool valid = keys[SN - 1 - i] != 0ull;
            uint32_t ov = (tid < 10) ? (rowm[i * 10 + tid] & M) : 0u;
            bool sup = __any(ov != 0u);
            bool keep = valid && !sup;
            if (keep && tid == (i >> 5)) M |= (1u << (i & 31));
            if (tid == 0) kept[i] = keep ? 1 : 0;
        }
    }
    __syncthreads();

    for (int r = tid; r < TOPK; r += 512) {
        uint64_t sk = keys[SN - 1 - r];
        uint32_t flat = (uint32_t)c * TOPK + (uint32_t)r;
        uint32_t n = sk ? ~(uint32_t)sk : 0u;
        nsel[(size_t)b * FLATN + flat] = (int)n;
        staged[(size_t)b * FLATN + flat] =
            (kept[r] ? ((sk & 0xFFFFFFFF00000000ull) | (uint64_t)(~flat)) : 0ull);
    }
}

// ---------- K6: per-image top-300 via 64-step value binary search (register keys) ----------
__global__ __launch_bounds__(1024) void k6_final(const float* __restrict__ boxes,
                                                 const uint64_t* __restrict__ staged,
                                                 const int* __restrict__ nsel,
                                                 float* __restrict__ out) {
    __shared__ uint32_t wsum[2][16];
    __shared__ uint64_t sel[512];
    __shared__ uint64_t rankedKey[TOPK];
    __shared__ uint32_t selCount;
    const int tid = threadIdx.x;
    const int lane = tid & 63;
    const int wid = tid >> 6;
    const int b = blockIdx.x;
    const uint64_t* keys = staged + (size_t)b * FLATN;

    // load 24000 keys once into registers (coalesced, statically indexed)
    uint64_t kk[24];
#pragma unroll
    for (int j = 0; j < 24; ++j) {
        int i = tid + j * 1024;
        kk[j] = (i < FLATN) ? keys[i] : 0ull;
    }
    if (tid == 0) selCount = 0;
    for (int i = tid; i < 512; i += 1024) sel[i] = 0ull;
    for (int i = tid; i < TOPK; i += 1024) rankedKey[i] = 0ull;

    // count nonzero -> need
    {
        int c = 0;
#pragma unroll
        for (int j = 0; j < 24; ++j) c += (kk[j] != 0ull) ? 1 : 0;
#pragma unroll
        for (int off = 32; off > 0; off >>= 1) c += __shfl_down(c, off);
        if (lane == 0) wsum[0][wid] = (uint32_t)c;
    }
    __syncthreads();
    uint32_t total = 0;
#pragma unroll
    for (int w = 0; w < 16; ++w) total += wsum[0][w];
    const uint32_t need = total < (uint32_t)TOPK ? total : (uint32_t)TOPK;

    // binary search for T* = need-th largest key (keys unique, nonzero)
    // invariant: cnt(>= lo) >= need, cnt(>= hi) < need
    uint64_t lo = 1ull, hi = ~0ull;
    int par = 1;
    for (int it = 0; it < 64; ++it) {
        uint64_t mid = lo + ((hi - lo) >> 1);
        int c = 0;
#pragma unroll
        for (int j = 0; j < 24; ++j) c += (kk[j] >= mid) ? 1 : 0;
#pragma unroll
        for (int off = 32; off > 0; off >>= 1) c += __shfl_down(c, off);
        if (lane == 0) wsum[par][wid] = (uint32_t)c;
        __syncthreads();
        uint32_t tot = 0;
#pragma unroll
        for (int w = 0; w < 16; ++w) tot += wsum[par][w];
        if (tot >= need) lo = mid; else hi = mid;
        par ^= 1;
    }
    const uint64_t thresh = lo;  // cnt(>= thresh) == need (0 if need == 0 -> none match)

    // collect selected (exactly `need` <= 300 when need > 0)
    if (need > 0) {
#pragma unroll
        for (int j = 0; j < 24; ++j) {
            uint64_t v = kk[j];
            if (v >= thresh && v != 0ull) {
                uint32_t pos = atomicAdd(&selCount, 1u);
                if (pos < 512) sel[pos] = v;
            }
        }
    }
    __syncthreads();

    // rank-by-counting (keys unique; sel[j2] reads broadcast across lanes)
    for (int s = tid; s < 512; s += 1024) {
        uint64_t mine = sel[s];
        if (mine != 0ull) {
            int rank = 0;
            for (int j2 = 0; j2 < 512; ++j2) rank += (sel[j2] > mine) ? 1 : 0;
            if (rank < TOPK) rankedKey[rank] = mine;
        }
    }
    __syncthreads();

    float* outBoxes = out;
    float* outScores = out + BATCH * TOPK * 4;
    float* outLabels = out + BATCH * TOPK * 4 + BATCH * TOPK;
    for (int r0 = tid; r0 < TOPK; r0 += 1024) {
        uint64_t kkv = rankedKey[r0];
        if (kkv != 0ull) {
            uint32_t flat = ~(uint32_t)kkv;
            uint32_t c = flat / TOPK;
            uint32_t n = (uint32_t)nsel[(size_t)b * FLATN + flat];
            float4 bx = reinterpret_cast<const float4*>(boxes)[(size_t)b * NANCH + n];
            reinterpret_cast<float4*>(outBoxes)[(size_t)b * TOPK + r0] = bx;
            outScores[b * TOPK + r0] = __uint_as_float((uint32_t)(kkv >> 32));
            outLabels[b * TOPK + r0] = (float)c;
        } else {
            reinterpret_cast<float4*>(outBoxes)[(size_t)b * TOPK + r0] =
                make_float4(-1.0f, -1.0f, -1.0f, -1.0f);
            outScores[b * TOPK + r0] = -1.0f;
            outLabels[b * TOPK + r0] = -1.0f;
        }
    }
}

extern "C" void kernel_launch(void* const* d_in, const int* in_sizes, int n_in,
                              void* d_out, int out_size, void* d_ws, size_t ws_size,
                              hipStream_t stream) {
    const float* boxes = (const float*)d_in[0];          // [2,100000,4]
    const float* cls   = (const float*)d_in[1];          // [2,100000,80]
    float* out = (float*)d_out;                          // 3600 floats
    char* ws = (char*)d_ws;

    size_t off = 0;
    uint32_t* blockcnt = (uint32_t*)(ws + off);
    off += (size_t)NSLICE * NBPAD * 4;                   // 1,310,720
    uint32_t* blockbase = (uint32_t*)(ws + off);
    off += (size_t)NSLICE * NBPAD * 4;                   // 1,310,720
    uint32_t* ccount = (uint32_t*)(ws + off); off += 4096;
    uint64_t* cand = (uint64_t*)(ws + off);
    off += (size_t)NSLICE * CAND * 8;                    // 2,621,440
    uint64_t* staged = (uint64_t*)(ws + off);
    off += (size_t)BATCH * FLATN * 8;                    // 384,000
    int* nsel = (int*)(ws + off);
    off += (size_t)BATCH * FLATN * 4;                    // 192,000

    k1_count<<<NBLK, 256, 0, stream>>>(cls, blockcnt);
    k2_scan<<<NSLICE, 256, 0, stream>>>(blockcnt, blockbase, ccount);
    k3_emit<<<NBLK, 256, 0, stream>>>(cls, blockbase, cand);
    k4_fixup<<<NSLICE, 256, 0, stream>>>(cls, ccount, cand);
    k5_nms<<<NSLICE, 512, 0, stream>>>(boxes, ccount, cand, staged, nsel);
    k6_final<<<BATCH, 1024, 0, stream>>>(boxes, staged, nsel, out);
}